// Round 7
// baseline (190.987 us; speedup 1.0000x reference)
//
#include <hip/hip_runtime.h>
#include <math.h>

// Problem constants
#define B_  4
#define S_  2048
#define H_  1024
#define D_  64
#define ROWS (B_*S_)      // 8192
#define LOG2E 1.4426950408889634f

typedef __attribute__((ext_vector_type(4))) float  floatx4;
typedef __attribute__((ext_vector_type(8))) short  short8;
typedef __attribute__((ext_vector_type(8))) __bf16 bf16x8;

// ---- workspace layout ----
// float region (offsets in floats):
#define WS_KSUM 0                          // [B][D]
#define WS_M    (WS_KSUM + B_*D_)          // [B][D][D]  K^T K per batch
#define WS_FEND (WS_M + B_*D_*D_)          // floats (x4 B = 16B-aligned)
// bf16(short) region, starts right after the float region.
#define WB_QB  0                           // [ROWS][64] row-major (attn Q-frags + rowstats)
#define WB_KF  (WB_QB + ROWS*D_)           // [ROWS/16][kh2][64][8]  K A-frags
#define WB_VF  (WB_KF + ROWS*D_)           // [ROWS/64][nt4][kh2][64][8]  V B-frags
#define WB_WT  (WB_VF + ROWS*D_)           // [3][32 kc][4 nt][64][8]  W B-frags
#define WB_WFF (WB_WT + 3*D_*H_)           // [H/16][2][64][8]  Weff B-frags
#define NZ2    (B_*D_ + B_*D_*D_)          // zeroed atomically-accumulated range

__device__ __forceinline__ unsigned short f2bf(float f) {
    union { float f; unsigned u; } v; v.f = f;
    unsigned r = v.u + 0x7FFFu + ((v.u >> 16) & 1u);   // RNE
    return (unsigned short)(r >> 16);
}
__device__ __forceinline__ short bfc(float f) {        // HW cvt (RNE) path
    __bf16 h = (__bf16)f;
    short s; __builtin_memcpy(&s, &h, 2); return s;
}
__device__ __forceinline__ float bf2f(short s) {
    union { unsigned u; float f; } v;
    v.u = ((unsigned)(unsigned short)s) << 16; return v.f;
}
__device__ __forceinline__ bf16x8 ldb(const short* p) {
    union { short8 s; bf16x8 b; } u; u.s = *(const short8*)p; return u.b;
}
__device__ __forceinline__ bf16x8 s2b(short8 s) {
    union { short8 s; bf16x8 b; } u; u.s = s; return u.b;
}
#define MFMA(a,b,c) __builtin_amdgcn_mfma_f32_16x16x32_bf16(a, b, c, 0, 0, 0)
// per-wave LDS ordering fence: lgkmcnt(0) only, vmcnt stays in flight
__device__ __forceinline__ void lds_fence() {
    __builtin_amdgcn_wave_barrier();
    __builtin_amdgcn_s_waitcnt(0xc07f);
    __builtin_amdgcn_wave_barrier();
}

// ---------------------------------------------------------------------------
// 1) prep:
//    bx [0,96):    WT3 fragment-major gather of Wq/Wk/Wv (bf16)
//    bx [96,112):  WFF = fragment-major bf16 of Weff^T (sum of Wout blocks)
//    bx [112,177): zero KSUM+M
__global__ __launch_bounds__(256) void prep(
    const float* __restrict__ Wq, const float* __restrict__ Wk,
    const float* __restrict__ Wv, const float* __restrict__ Wout,
    float* __restrict__ wsf)
{
    __shared__ float tile[64][65];
    short* wsb = (short*)(wsf + WS_FEND);
    const int bx = blockIdx.x, t = threadIdx.x;
    if (bx < 96) {
        int idx = bx * 256 + t;              // slot < 3*32*4*64
        int mat = idx >> 13, rem = idx & 8191;
        int kc = rem >> 8, nt = (rem >> 6) & 3, lane = rem & 63;
        int g = lane >> 4, l15 = lane & 15;
        const float* W = (mat == 0) ? Wq : (mat == 1) ? Wk : Wv;
        short8 fr;
        #pragma unroll
        for (int j = 0; j < 8; ++j)
            fr[j] = (short)f2bf(W[(size_t)(kc*32 + g*8 + j) * D_ + nt*16 + l15]);
        *(short8*)&wsb[WB_WT + (size_t)idx * 8] = fr;
    } else if (bx < 112) {
        // Weff[d][n] = sum_h Wout[h*64+d][n]
        int n0 = (bx - 96) * 64;
        int nn = t & 63, dg = t >> 6;
        for (int dd = 0; dd < 16; ++dd) {
            int d = dg * 16 + dd;
            float s = 0.0f;
            #pragma unroll
            for (int h = 0; h < 16; ++h)
                s += Wout[(size_t)(h * 64 + d) * H_ + n0 + nn];
            tile[d][nn] = s;
        }
        __syncthreads();
        #pragma unroll
        for (int u = 0; u < 2; ++u) {
            int s = 2*t + u;                 // slot < 512
            int ctl = s >> 7, h = (s >> 6) & 1, lane = s & 63;
            int g = lane >> 4, l2 = lane & 15;
            short8 fr;
            #pragma unroll
            for (int j = 0; j < 8; ++j)
                fr[j] = (short)f2bf(tile[h*32 + g*8 + j][ctl*16 + l2]);
            *(short8*)&wsb[WB_WFF + (size_t)((((n0 >> 4) + ctl)*2 + h)*64 + lane) * 8] = fr;
        }
    } else {
        int i = (bx - 112) * 256 + t;
        if (i < NZ2) wsf[WS_KSUM + i] = 0.0f;
    }
}

// ---------------------------------------------------------------------------
// 2) q/k/v = bf16(X @ W + b) via MFMA.  grid (ROWS/32, 3), block 256.
//    X staging: LDS dbuf + TWO register prefetch sets (ra/rb), 2-step-unrolled
//    loop -> each set's global load is issued 2 iterations before its LDS
//    store and stays in flight across two MFMA phases (~500 cy) -> HBM
//    latency fully hidden.  mat==1 blocks accumulate KSUM and M = K^T K via
//    MFMA (4/wave, K=32).
__global__ __launch_bounds__(256) void qkv_mfma(
    const float* __restrict__ query, const float* __restrict__ key,
    const float* __restrict__ value,
    const float* __restrict__ bq, const float* __restrict__ bk,
    const float* __restrict__ bvp, float* __restrict__ wsf)
{
    short* wsb = (short*)(wsf + WS_FEND);
    const int mat = blockIdx.y;
    const float* X    = (mat == 0) ? query : (mat == 1) ? key : value;
    const float* bias = (mat == 0) ? bq    : (mat == 1) ? bk  : bvp;
    const short* WT3 = wsb + WB_WT + (size_t)mat * (D_ * H_);

    const int t = threadIdx.x, w = t >> 6, lane = t & 63;
    const int l15 = lane & 15, g = lane >> 4;
    const int r0 = blockIdx.x * 32;
    const int mrow0 = (w >> 1) * 16;
    const int nt0 = (w & 1) * 2;

    __shared__ short xs[2][32][136];  // dbuf bf16 X tile, stride 136
    __shared__ float kf[32][65];      // fp32 K tile (bf16-rounded) for kstats
    floatx4 acc[2] = {};

    const int lrow = t >> 5;          // 0..7
    const int lcol = (t & 31) * 4;
    const float* Xb = &X[(size_t)r0 * H_];

    auto LD = [&](float4* r, int step) {
        #pragma unroll
        for (int u = 0; u < 4; ++u)
            r[u] = *(const float4*)&Xb[(size_t)(u*8 + lrow) * H_ + step * 128 + lcol];
    };
    auto ST = [&](const float4* r, int p) {
        #pragma unroll
        for (int u = 0; u < 4; ++u) {
            short4 pk;
            pk.x = bfc(r[u].x); pk.y = bfc(r[u].y);
            pk.z = bfc(r[u].z); pk.w = bfc(r[u].w);
            *(short4*)&xs[p][u*8 + lrow][lcol] = pk;
        }
    };
    auto MM = [&](int p, int step) {
        #pragma unroll
        for (int kk = 0; kk < 4; ++kk) {
            bf16x8 a = ldb(&xs[p][mrow0 + l15][kk * 32 + g * 8]);
            int kc = step * 4 + kk;
            #pragma unroll
            for (int n = 0; n < 2; ++n) {
                bf16x8 bf = ldb(&WT3[(size_t)((kc * 4) + nt0 + n) * 512 + lane * 8]);
                acc[n] = MFMA(a, bf, acc[n]);
            }
        }
    };

    float4 ra[4], rb[4];
    LD(ra, 0); LD(rb, 1);
    #pragma unroll
    for (int s2 = 0; s2 < 4; ++s2) {
        __syncthreads();                 // WAR on xs[0]
        ST(ra, 0);
        if (s2 < 3) LD(ra, 2*s2 + 2);    // in flight across 2 MFMA phases
        __syncthreads();                 // RAW xs[0]
        MM(0, 2*s2);
        __syncthreads();                 // WAR on xs[1]
        ST(rb, 1);
        if (s2 < 3) LD(rb, 2*s2 + 3);
        __syncthreads();                 // RAW xs[1]
        MM(1, 2*s2 + 1);
    }

    // epilogue: C layout row=4g+r (in 16-tile), col=l15
    if (mat == 0) {
        short* QB = wsb + WB_QB;
        #pragma unroll
        for (int n = 0; n < 2; ++n) {
            int col = (nt0 + n) * 16 + l15;
            float bb = bias[col];
            #pragma unroll
            for (int r = 0; r < 4; ++r)
                QB[(size_t)(r0 + mrow0 + 4*g + r) * D_ + col] = (short)f2bf(acc[n][r] + bb);
        }
    } else if (mat == 1) {
        short* KFp = wsb + WB_KF;
        #pragma unroll
        for (int n = 0; n < 2; ++n) {
            int d = (nt0 + n) * 16 + l15;
            int kh = d >> 5, gk = (d >> 3) & 3, j = d & 7;
            float bb = bias[d];
            #pragma unroll
            for (int r = 0; r < 4; ++r) {
                int R = r0 + mrow0 + 4*g + r;
                unsigned short hv = f2bf(acc[n][r] + bb);
                KFp[(size_t)(((R >> 4) * 2 + kh) * 64 + gk * 16 + (R & 15)) * 8 + j] =
                    (short)hv;
                kf[mrow0 + 4*g + r][d] = bf2f((short)hv);  // same rounding as KF
            }
        }
        __syncthreads();
        // --- fused kstats via MFMA: M[b] += Ktile^T Ktile (16 tiles, 4/wave) ---
        const int b = r0 >> 11;
        const int gj = g * 8;
        short8 ts;
        bf16x8 fb[4];
        #pragma unroll
        for (int i = 0; i < 4; ++i) {
            #pragma unroll
            for (int j = 0; j < 8; ++j)
                ts[j] = bfc(kf[gj + j][i*16 + l15]);
            fb[i] = s2b(ts);
        }
        #pragma unroll
        for (int j = 0; j < 8; ++j)
            ts[j] = bfc(kf[gj + j][w*16 + l15]);
        bf16x8 fa = s2b(ts);
        float* M = wsf + WS_M + (size_t)b * D_ * D_;
        #pragma unroll
        for (int i2 = 0; i2 < 4; ++i2) {
            floatx4 z = {};
            floatx4 mt = MFMA(fa, fb[i2], z);
            #pragma unroll
            for (int r = 0; r < 4; ++r)
                atomicAdd(&M[(size_t)(w*16 + 4*g + r) * D_ + i2*16 + l15], mt[r]);
        }
        if (t < 64) {
            float s = 0.0f;
            #pragma unroll
            for (int jj = 0; jj < 32; ++jj) s += kf[jj][t];
            atomicAdd(&wsf[WS_KSUM + b * D_ + t], s);
        }
    } else {
        short* VF = wsb + WB_VF;
        int R0 = r0 + mrow0 + 4*g;
        int kh = (R0 >> 5) & 1, gv = (R0 >> 3) & 3, j0 = R0 & 7, blk = R0 >> 6;
        #pragma unroll
        for (int n = 0; n < 2; ++n) {
            int d = (nt0 + n) * 16 + l15;
            int ntv = d >> 4;
            float bb = bias[d];
            short4 pk;
            pk.x = (short)f2bf(acc[n][0] + bb); pk.y = (short)f2bf(acc[n][1] + bb);
            pk.z = (short)f2bf(acc[n][2] + bb); pk.w = (short)f2bf(acc[n][3] + bb);
            *(short4*)&VF[(size_t)(((blk * 4 + ntv) * 2 + kh) * 64 + gv * 16 + (d & 15)) * 8 + j0] = pk;
        }
    }
}

// ---------------------------------------------------------------------------
// 3) Fully-fused rowstats + attention + output GEMM.
//    grid ROWS/32 = 256 blocks, block 512 (8 waves).
//    Block owns 32 q-rows (2 q-tiles/wave); wave w covers keys
//    [w*256,(w+1)*256).  Halves K/V L2 traffic and rowstats work vs the
//    16-row variant.  In-LDS reduce of the 8 waves' O/sumw partials ->
//    HN A-frags -> out = HN @ Weff + bout.
__global__ __launch_bounds__(512, 2) void attn_fused(
    const float* __restrict__ bout, float* __restrict__ wsf,
    float* __restrict__ out)
{
    short* wsb = (short*)(wsf + WS_FEND);
    const short* Qb  = wsb + WB_QB;
    const short* KF  = wsb + WB_KF;
    const short* VF  = wsb + WB_VF;
    const short* WFF = wsb + WB_WFF;

    __shared__ short P[8][32][72];      // per-wave [32 q][64 keys]
    __shared__ short OL[8][32][64];     // per-wave O partial (bf16)
    __shared__ float sumwL[8][32];      // per-wave softmax denominators
    __shared__ short hnF[2*2*64*8];     // HN A-frags [rb2][kh][64][8]
    __shared__ float smA[32], smC[32];  // layernorm coefficients

    const int t = threadIdx.x, w = t >> 6, lane = t & 63;
    const int l15 = lane & 15, g = lane >> 4;
    const int q0 = blockIdx.x * 32;
    const int b  = blockIdx.x >> 6;                 // 64 blocks per batch

    // --- fused rowstats prologue: wave w handles rows q0+w*4..+3 ---
    {
        const int rw = q0 + w * 4;
        const float* M = wsf + WS_M + (size_t)b * D_ * D_;
        float qv[4], y[4] = {};
        #pragma unroll
        for (int r = 0; r < 4; ++r) qv[r] = bf2f(Qb[(size_t)(rw + r) * D_ + lane]);
        for (int d2 = 0; d2 < 64; ++d2) {
            float m = M[d2 * D_ + lane];
            #pragma unroll
            for (int r = 0; r < 4; ++r) y[r] += __shfl(qv[r], d2, 64) * m;
        }
        float kl = wsf[WS_KSUM + b * D_ + lane];
        float z[4], sv[4];
        #pragma unroll
        for (int r = 0; r < 4; ++r) { z[r] = y[r] * qv[r]; sv[r] = qv[r] * kl; }
        #pragma unroll
        for (int m = 1; m < 64; m <<= 1) {
            #pragma unroll
            for (int r = 0; r < 4; ++r) {
                z[r]  += __shfl_xor(z[r],  m, 64);
                sv[r] += __shfl_xor(sv[r], m, 64);
            }
        }
        #pragma unroll
        for (int r = 0; r < 4; ++r) {
            if (lane == r) {
                float sum   = sv[r] * (1.0f / 32.0f);
                float sumsq = z[r]  * (1.0f / 1024.0f);
                float mu  = sum * (1.0f / 2048.0f);
                float var = (sumsq - sum * sum * (1.0f / 2048.0f)) * (1.0f / 2047.0f);
                var = fmaxf(var, 0.0f);
                float inv = 1.0f / (sqrtf(var) + 1e-8f);
                smA[w*4 + r] = inv * (LOG2E / 32.0f);
                smC[w*4 + r] = -mu * inv * LOG2E;
            }
        }
    }

    // preload Q B-frags (B[d][q]) while the prologue settles
    bf16x8 bqf[2][2];
    #pragma unroll
    for (int nt = 0; nt < 2; ++nt)
        #pragma unroll
        for (int h = 0; h < 2; ++h)
            bqf[nt][h] = ldb(&Qb[(size_t)(q0 + nt*16 + l15) * D_ + h*32 + g*8]);
    __syncthreads();
    const float a2v[2] = { smA[l15], smA[16 + l15] };
    const float c2v[2] = { smC[l15], smC[16 + l15] };

    floatx4 O[2][4] = {};
    float sacc[2] = {0.0f, 0.0f};
    short* Pw = &P[w][0][0];

    for (int kc = 0; kc < 256; kc += 64) {
        const int key0 = w * 256 + kc;
        const int kblk16 = (b * S_ + key0) >> 4;
        const int kblk64 = (b * S_ + key0) >> 6;
        // --- S^T tiles: Sc[kt][nt], D[key][q] ---
        floatx4 Sc[4][2] = {};
        __builtin_amdgcn_s_setprio(1);
        #pragma unroll
        for (int kt = 0; kt < 4; ++kt) {
            bf16x8 ak0 = ldb(&KF[(size_t)(((kblk16 + kt) * 2 + 0) * 64 + lane) * 8]);
            bf16x8 ak1 = ldb(&KF[(size_t)(((kblk16 + kt) * 2 + 1) * 64 + lane) * 8]);
            #pragma unroll
            for (int nt = 0; nt < 2; ++nt) {
                Sc[kt][nt] = MFMA(ak0, bqf[nt][0], Sc[kt][nt]);
                Sc[kt][nt] = MFMA(ak1, bqf[nt][1], Sc[kt][nt]);
            }
        }
        __builtin_amdgcn_s_setprio(0);
        lds_fence();   // WAR: previous chunk's P reads must finish (wave-private P)
        // --- exp2 + pack bf16 + write P[q][key] ---
        #pragma unroll
        for (int nt = 0; nt < 2; ++nt) {
            const float aa = a2v[nt], cc = c2v[nt];
            #pragma unroll
            for (int kt = 0; kt < 4; ++kt) {
                float w0 = __builtin_amdgcn_exp2f(fmaf(Sc[kt][nt][0], aa, cc));
                float w1 = __builtin_amdgcn_exp2f(fmaf(Sc[kt][nt][1], aa, cc));
                float w2 = __builtin_amdgcn_exp2f(fmaf(Sc[kt][nt][2], aa, cc));
                float w3 = __builtin_amdgcn_exp2f(fmaf(Sc[kt][nt][3], aa, cc));
                sacc[nt] += (w0 + w1) + (w2 + w3);
                short4 pk;
                pk.x = bfc(w0); pk.y = bfc(w1); pk.z = bfc(w2); pk.w = bfc(w3);
                *(short4*)&Pw[(nt*16 + l15) * 72 + kt*16 + 4*g] = pk;
            }
        }
        lds_fence();   // RAW: make P visible to all lanes of this wave
        // --- PV: O[q][d] += P.V ---
        bf16x8 ap[2][2];
        #pragma unroll
        for (int mt = 0; mt < 2; ++mt)
            #pragma unroll
            for (int kh = 0; kh < 2; ++kh)
                ap[mt][kh] = ldb(&Pw[(mt*16 + l15) * 72 + kh*32 + g*8]);
        __builtin_amdgcn_s_setprio(1);
        #pragma unroll
        for (int nt = 0; nt < 4; ++nt) {
            bf16x8 bv0 = ldb(&VF[(size_t)(((kblk64 * 4 + nt) * 2 + 0) * 64 + lane) * 8]);
            bf16x8 bv1 = ldb(&VF[(size_t)(((kblk64 * 4 + nt) * 2 + 1) * 64 + lane) * 8]);
            #pragma unroll
            for (int mt = 0; mt < 2; ++mt) {
                O[mt][nt] = MFMA(ap[mt][0], bv0, O[mt][nt]);
                O[mt][nt] = MFMA(ap[mt][1], bv1, O[mt][nt]);
            }
        }
        __builtin_amdgcn_s_setprio(0);
    }

    // --- per-wave epilogue: reduce sumw over g-groups; stash partials ---
    #pragma unroll
    for (int nt = 0; nt < 2; ++nt) {
        sacc[nt] += __shfl_xor(sacc[nt], 16, 64);
        sacc[nt] += __shfl_xor(sacc[nt], 32, 64);
    }
    if (lane < 16) {
        sumwL[w][lane]      = sacc[0];
        sumwL[w][16 + lane] = sacc[1];
    }
    #pragma unroll
    for (int mt = 0; mt < 2; ++mt)
        #pragma unroll
        for (int nt = 0; nt < 4; ++nt)
            #pragma unroll
            for (int r = 0; r < 4; ++r)
                OL[w][mt*16 + 4*g + r][nt*16 + l15] = (short)f2bf(O[mt][nt][r]);
    __syncthreads();

    // --- block reduce: HN = (sum_w OL) / (sum_w sumw) -> A-frags in LDS ---
    {
        const int row = t >> 4;            // 0..31
        const int c = (t & 15) * 4;        // 0..60
        float s0 = 0.f, s1 = 0.f, s2 = 0.f, s3 = 0.f, sw = 0.f;
        #pragma unroll
        for (int p = 0; p < 8; ++p) {
            short4 o = *(const short4*)&OL[p][row][c];
            s0 += bf2f(o.x); s1 += bf2f(o.y); s2 += bf2f(o.z); s3 += bf2f(o.w);
            sw += sumwL[p][row];
        }
        float inv = 1.0f / sw;
        short4 hn;
        hn.x = (short)f2bf(s0 * inv); hn.y = (short)f2bf(s1 * inv);
        hn.z = (short)f2bf(s2 * inv); hn.w = (short)f2bf(s3 * inv);
        int rb2 = row >> 4, r15 = row & 15;
        int kh = c >> 5, g2 = (c >> 3) & 3, j0 = c & 7;
        *(short4*)&hnF[(size_t)(((rb2*2 + kh) * 64) + g2*16 + r15) * 8 + j0] = hn;
    }
    __syncthreads();

    // --- out tile [32 x 1024] = HN @ Weff + bout; wave w owns 8 n-tiles ---
    bf16x8 ah[2][2];
    #pragma unroll
    for (int rb2 = 0; rb2 < 2; ++rb2)
        #pragma unroll
        for (int kh = 0; kh < 2; ++kh)
            ah[rb2][kh] = ldb(&hnF[(size_t)((rb2*2 + kh) * 64 + lane) * 8]);
    #pragma unroll
    for (int i = 0; i < 8; ++i) {
        int n16 = w * 8 + i;
        bf16x8 bf0 = ldb(&WFF[(size_t)(n16 * 2 + 0) * 512 + lane * 8]);
        bf16x8 bf1 = ldb(&WFF[(size_t)(n16 * 2 + 1) * 512 + lane * 8]);
        int col = n16 * 16 + l15;
        float bb = bout[col];
        #pragma unroll
        for (int rb2 = 0; rb2 < 2; ++rb2) {
            floatx4 acc = {};
            acc = MFMA(ah[rb2][0], bf0, acc);
            acc = MFMA(ah[rb2][1], bf1, acc);
            #pragma unroll
            for (int r = 0; r < 4; ++r)
                out[(size_t)(q0 + rb2*16 + 4*g + r) * H_ + col] = acc[r] + bb;
        }
    }
}

// ---------------------------------------------------------------------------
extern "C" void kernel_launch(void* const* d_in, const int* in_sizes, int n_in,
                              void* d_out, int out_size, void* d_ws, size_t ws_size,
                              hipStream_t stream) {
    const float* query = (const float*)d_in[0];
    const float* key   = (const float*)d_in[1];
    const float* value = (const float*)d_in[2];
    // d_in[3] mask / d_in[12] seq_mask: adding -1e-32 is a no-op in fp32 -> never read.
    const float* Wq   = (const float*)d_in[4];
    const float* bq   = (const float*)d_in[5];
    const float* Wk   = (const float*)d_in[6];
    const float* bk   = (const float*)d_in[7];
    const float* Wv   = (const float*)d_in[8];
    const float* bv   = (const float*)d_in[9];
    const float* Wout = (const float*)d_in[10];
    const float* bout = (const float*)d_in[11];

    float* ws  = (float*)d_ws;
    float* out = (float*)d_out;

    prep<<<177, 256, 0, stream>>>(Wq, Wk, Wv, Wout, ws);
    qkv_mfma<<<dim3(ROWS/32, 3), 256, 0, stream>>>(query, key, value, bq, bk, bv, ws);
    attn_fused<<<ROWS/32, 512, 0, stream>>>(bout, ws, out);
}

// Round 10
// 186.415 us; speedup vs baseline: 1.0245x; 1.0245x over previous
//
#include <hip/hip_runtime.h>
#include <math.h>

// Problem constants
#define B_  4
#define S_  2048
#define H_  1024
#define D_  64
#define ROWS (B_*S_)      // 8192
#define LOG2E 1.4426950408889634f

typedef __attribute__((ext_vector_type(4))) float  floatx4;
typedef __attribute__((ext_vector_type(8))) short  short8;
typedef __attribute__((ext_vector_type(8))) __bf16 bf16x8;

// ---- workspace layout ----
// float region (offsets in floats):
#define WS_KSUM 0                          // [B][D]
#define WS_M    (WS_KSUM + B_*D_)          // [B][D][D]  K^T K per batch
#define WS_FEND (WS_M + B_*D_*D_)          // floats (x4 B = 16B-aligned)
// bf16(short) region, starts right after the float region.
#define WB_QB  0                           // [ROWS][64] row-major (attn Q-frags + rowstats)
#define WB_KF  (WB_QB + ROWS*D_)           // [ROWS/16][kh2][64][8]  K A-frags
#define WB_VF  (WB_KF + ROWS*D_)           // [ROWS/64][nt4][kh2][64][8]  V B-frags
#define WB_WT  (WB_VF + ROWS*D_)           // [3][32 kc][4 nt][64][8]  W B-frags
#define WB_WFF (WB_WT + 3*D_*H_)           // [H/16][2][64][8]  Weff B-frags
#define NZ2    (B_*D_ + B_*D_*D_)          // zeroed atomically-accumulated range

__device__ __forceinline__ unsigned short f2bf(float f) {
    union { float f; unsigned u; } v; v.f = f;
    unsigned r = v.u + 0x7FFFu + ((v.u >> 16) & 1u);   // RNE
    return (unsigned short)(r >> 16);
}
__device__ __forceinline__ short bfc(float f) {        // HW cvt (RNE) path
    __bf16 h = (__bf16)f;
    short s; __builtin_memcpy(&s, &h, 2); return s;
}
__device__ __forceinline__ float bf2f(short s) {
    union { unsigned u; float f; } v;
    v.u = ((unsigned)(unsigned short)s) << 16; return v.f;
}
__device__ __forceinline__ bf16x8 ldb(const short* p) {
    union { short8 s; bf16x8 b; } u; u.s = *(const short8*)p; return u.b;
}
__device__ __forceinline__ bf16x8 s2b(short8 s) {
    union { short8 s; bf16x8 b; } u; u.s = s; return u.b;
}
#define MFMA(a,b,c) __builtin_amdgcn_mfma_f32_16x16x32_bf16(a, b, c, 0, 0, 0)
// per-wave LDS ordering fence: lgkmcnt(0) only, vmcnt stays in flight
__device__ __forceinline__ void lds_fence() {
    __builtin_amdgcn_wave_barrier();
    __builtin_amdgcn_s_waitcnt(0xc07f);
    __builtin_amdgcn_wave_barrier();
}

// ---------------------------------------------------------------------------
// 1) prep:
//    bx [0,96):    WT3 fragment-major gather of Wq/Wk/Wv (bf16)
//    bx [96,112):  WFF = fragment-major bf16 of Weff^T (sum of Wout blocks)
//    bx [112,177): zero KSUM+M
__global__ __launch_bounds__(256) void prep(
    const float* __restrict__ Wq, const float* __restrict__ Wk,
    const float* __restrict__ Wv, const float* __restrict__ Wout,
    float* __restrict__ wsf)
{
    __shared__ float tile[64][65];
    short* wsb = (short*)(wsf + WS_FEND);
    const int bx = blockIdx.x, t = threadIdx.x;
    if (bx < 96) {
        int idx = bx * 256 + t;              // slot < 3*32*4*64
        int mat = idx >> 13, rem = idx & 8191;
        int kc = rem >> 8, nt = (rem >> 6) & 3, lane = rem & 63;
        int g = lane >> 4, l15 = lane & 15;
        const float* W = (mat == 0) ? Wq : (mat == 1) ? Wk : Wv;
        short8 fr;
        #pragma unroll
        for (int j = 0; j < 8; ++j)
            fr[j] = (short)f2bf(W[(size_t)(kc*32 + g*8 + j) * D_ + nt*16 + l15]);
        *(short8*)&wsb[WB_WT + (size_t)idx * 8] = fr;
    } else if (bx < 112) {
        // Weff[d][n] = sum_h Wout[h*64+d][n]
        int n0 = (bx - 96) * 64;
        int nn = t & 63, dg = t >> 6;
        for (int dd = 0; dd < 16; ++dd) {
            int d = dg * 16 + dd;
            float s = 0.0f;
            #pragma unroll
            for (int h = 0; h < 16; ++h)
                s += Wout[(size_t)(h * 64 + d) * H_ + n0 + nn];
            tile[d][nn] = s;
        }
        __syncthreads();
        #pragma unroll
        for (int u = 0; u < 2; ++u) {
            int s = 2*t + u;                 // slot < 512
            int ctl = s >> 7, h = (s >> 6) & 1, lane = s & 63;
            int g = lane >> 4, l2 = lane & 15;
            short8 fr;
            #pragma unroll
            for (int j = 0; j < 8; ++j)
                fr[j] = (short)f2bf(tile[h*32 + g*8 + j][ctl*16 + l2]);
            *(short8*)&wsb[WB_WFF + (size_t)((((n0 >> 4) + ctl)*2 + h)*64 + lane) * 8] = fr;
        }
    } else {
        int i = (bx - 112) * 256 + t;
        if (i < NZ2) wsf[WS_KSUM + i] = 0.0f;
    }
}

// ---------------------------------------------------------------------------
// 2) q/k/v = bf16(X @ W + b) via MFMA.  grid (ROWS/32, 3), block 256.
//    X staging: LDS dbuf + TWO register prefetch sets (ra/rb), 2-step-unrolled
//    loop -> each set's global load is issued 2 iterations before its LDS
//    store and stays in flight across two MFMA phases (~500 cy) -> HBM
//    latency fully hidden.  mat==1 blocks accumulate KSUM and M = K^T K via
//    MFMA (4/wave, K=32).
__global__ __launch_bounds__(256) void qkv_mfma(
    const float* __restrict__ query, const float* __restrict__ key,
    const float* __restrict__ value,
    const float* __restrict__ bq, const float* __restrict__ bk,
    const float* __restrict__ bvp, float* __restrict__ wsf)
{
    short* wsb = (short*)(wsf + WS_FEND);
    const int mat = blockIdx.y;
    const float* X    = (mat == 0) ? query : (mat == 1) ? key : value;
    const float* bias = (mat == 0) ? bq    : (mat == 1) ? bk  : bvp;
    const short* WT3 = wsb + WB_WT + (size_t)mat * (D_ * H_);

    const int t = threadIdx.x, w = t >> 6, lane = t & 63;
    const int l15 = lane & 15, g = lane >> 4;
    const int r0 = blockIdx.x * 32;
    const int mrow0 = (w >> 1) * 16;
    const int nt0 = (w & 1) * 2;

    __shared__ short xs[2][32][136];  // dbuf bf16 X tile, stride 136
    __shared__ float kf[32][65];      // fp32 K tile (bf16-rounded) for kstats
    floatx4 acc[2] = {};

    const int lrow = t >> 5;          // 0..7
    const int lcol = (t & 31) * 4;
    const float* Xb = &X[(size_t)r0 * H_];

    auto LD = [&](float4* r, int step) {
        #pragma unroll
        for (int u = 0; u < 4; ++u)
            r[u] = *(const float4*)&Xb[(size_t)(u*8 + lrow) * H_ + step * 128 + lcol];
    };
    auto ST = [&](const float4* r, int p) {
        #pragma unroll
        for (int u = 0; u < 4; ++u) {
            short4 pk;
            pk.x = bfc(r[u].x); pk.y = bfc(r[u].y);
            pk.z = bfc(r[u].z); pk.w = bfc(r[u].w);
            *(short4*)&xs[p][u*8 + lrow][lcol] = pk;
        }
    };
    auto MM = [&](int p, int step) {
        #pragma unroll
        for (int kk = 0; kk < 4; ++kk) {
            bf16x8 a = ldb(&xs[p][mrow0 + l15][kk * 32 + g * 8]);
            int kc = step * 4 + kk;
            #pragma unroll
            for (int n = 0; n < 2; ++n) {
                bf16x8 bf = ldb(&WT3[(size_t)((kc * 4) + nt0 + n) * 512 + lane * 8]);
                acc[n] = MFMA(a, bf, acc[n]);
            }
        }
    };

    float4 ra[4], rb[4];
    LD(ra, 0); LD(rb, 1);
    #pragma unroll
    for (int s2 = 0; s2 < 4; ++s2) {
        __syncthreads();                 // WAR on xs[0]
        ST(ra, 0);
        if (s2 < 3) LD(ra, 2*s2 + 2);    // in flight across 2 MFMA phases
        __syncthreads();                 // RAW xs[0]
        MM(0, 2*s2);
        __syncthreads();                 // WAR on xs[1]
        ST(rb, 1);
        if (s2 < 3) LD(rb, 2*s2 + 3);
        __syncthreads();                 // RAW xs[1]
        MM(1, 2*s2 + 1);
    }

    // epilogue: C layout row=4g+r (in 16-tile), col=l15
    if (mat == 0) {
        short* QB = wsb + WB_QB;
        #pragma unroll
        for (int n = 0; n < 2; ++n) {
            int col = (nt0 + n) * 16 + l15;
            float bb = bias[col];
            #pragma unroll
            for (int r = 0; r < 4; ++r)
                QB[(size_t)(r0 + mrow0 + 4*g + r) * D_ + col] = (short)f2bf(acc[n][r] + bb);
        }
    } else if (mat == 1) {
        short* KFp = wsb + WB_KF;
        #pragma unroll
        for (int n = 0; n < 2; ++n) {
            int d = (nt0 + n) * 16 + l15;
            int kh = d >> 5, gk = (d >> 3) & 3, j = d & 7;
            float bb = bias[d];
            #pragma unroll
            for (int r = 0; r < 4; ++r) {
                int R = r0 + mrow0 + 4*g + r;
                unsigned short hv = f2bf(acc[n][r] + bb);
                KFp[(size_t)(((R >> 4) * 2 + kh) * 64 + gk * 16 + (R & 15)) * 8 + j] =
                    (short)hv;
                kf[mrow0 + 4*g + r][d] = bf2f((short)hv);  // same rounding as KF
            }
        }
        __syncthreads();
        // --- fused kstats via MFMA: M[b] += Ktile^T Ktile (16 tiles, 4/wave) ---
        const int b = r0 >> 11;
        const int gj = g * 8;
        short8 ts;
        bf16x8 fb[4];
        #pragma unroll
        for (int i = 0; i < 4; ++i) {
            #pragma unroll
            for (int j = 0; j < 8; ++j)
                ts[j] = bfc(kf[gj + j][i*16 + l15]);
            fb[i] = s2b(ts);
        }
        #pragma unroll
        for (int j = 0; j < 8; ++j)
            ts[j] = bfc(kf[gj + j][w*16 + l15]);
        bf16x8 fa = s2b(ts);
        float* M = wsf + WS_M + (size_t)b * D_ * D_;
        #pragma unroll
        for (int i2 = 0; i2 < 4; ++i2) {
            floatx4 z = {};
            floatx4 mt = MFMA(fa, fb[i2], z);
            #pragma unroll
            for (int r = 0; r < 4; ++r)
                atomicAdd(&M[(size_t)(w*16 + 4*g + r) * D_ + i2*16 + l15], mt[r]);
        }
        if (t < 64) {
            float s = 0.0f;
            #pragma unroll
            for (int jj = 0; jj < 32; ++jj) s += kf[jj][t];
            atomicAdd(&wsf[WS_KSUM + b * D_ + t], s);
        }
    } else {
        short* VF = wsb + WB_VF;
        int R0 = r0 + mrow0 + 4*g;
        int kh = (R0 >> 5) & 1, gv = (R0 >> 3) & 3, j0 = R0 & 7, blk = R0 >> 6;
        #pragma unroll
        for (int n = 0; n < 2; ++n) {
            int d = (nt0 + n) * 16 + l15;
            int ntv = d >> 4;
            float bb = bias[d];
            short4 pk;
            pk.x = (short)f2bf(acc[n][0] + bb); pk.y = (short)f2bf(acc[n][1] + bb);
            pk.z = (short)f2bf(acc[n][2] + bb); pk.w = (short)f2bf(acc[n][3] + bb);
            *(short4*)&VF[(size_t)(((blk * 4 + ntv) * 2 + kh) * 64 + gv * 16 + (d & 15)) * 8 + j0] = pk;
        }
    }
}

// ---------------------------------------------------------------------------
// 3) Fully-fused rowstats + attention + output GEMM.
//    grid ROWS/16 = 512 blocks, block 512 (8 waves).
//    Prologue: waves 0..3 compute layernorm coefficients (a2,c2) for the
//    block's 16 q-rows from M/KSUM (rowstats fused: removes one launch).
//    Main: wave w covers keys [w*256,(w+1)*256); in-LDS reduce of the 8
//    waves' O/sumw partials -> HN A-frags -> out = HN @ Weff + bout.
__global__ __launch_bounds__(512, 4) void attn_fused(
    const float* __restrict__ bout, float* __restrict__ wsf,
    float* __restrict__ out)
{
    short* wsb = (short*)(wsf + WS_FEND);
    const short* Qb  = wsb + WB_QB;
    const short* KF  = wsb + WB_KF;
    const short* VF  = wsb + WB_VF;
    const short* WFF = wsb + WB_WFF;

    __shared__ short P[8][16][72];    // per-wave [16 q][64 keys]
    __shared__ short OL[8][16][64];   // per-wave O partial (bf16)
    __shared__ float sumwL[8][16];    // per-wave softmax denominators
    __shared__ short hnF[2 * 64 * 8]; // HN A-frags of the 16-row tile
    __shared__ float smA[16], smC[16];// layernorm coefficients for the 16 rows

    const int t = threadIdx.x, w = t >> 6, lane = t & 63;
    const int l15 = lane & 15, g = lane >> 4;
    const int q0 = blockIdx.x * 16;
    const int b  = blockIdx.x >> 7;                 // 128 blocks per batch

    // --- fused rowstats prologue: waves 0..3 handle 4 rows each ---
    if (w < 4) {
        const int rw = q0 + w * 4;
        const float* M = wsf + WS_M + (size_t)b * D_ * D_;
        float qv[4], y[4] = {};
        #pragma unroll
        for (int r = 0; r < 4; ++r) qv[r] = bf2f(Qb[(size_t)(rw + r) * D_ + lane]);
        for (int d2 = 0; d2 < 64; ++d2) {
            float m = M[d2 * D_ + lane];
            #pragma unroll
            for (int r = 0; r < 4; ++r) y[r] += __shfl(qv[r], d2, 64) * m;
        }
        float kl = wsf[WS_KSUM + b * D_ + lane];
        float z[4], sv[4];
        #pragma unroll
        for (int r = 0; r < 4; ++r) { z[r] = y[r] * qv[r]; sv[r] = qv[r] * kl; }
        #pragma unroll
        for (int m = 1; m < 64; m <<= 1) {
            #pragma unroll
            for (int r = 0; r < 4; ++r) {
                z[r]  += __shfl_xor(z[r],  m, 64);
                sv[r] += __shfl_xor(sv[r], m, 64);
            }
        }
        #pragma unroll
        for (int r = 0; r < 4; ++r) {
            if (lane == r) {
                float sum   = sv[r] * (1.0f / 32.0f);
                float sumsq = z[r]  * (1.0f / 1024.0f);
                float mu  = sum * (1.0f / 2048.0f);
                float var = (sumsq - sum * sum * (1.0f / 2048.0f)) * (1.0f / 2047.0f);
                var = fmaxf(var, 0.0f);
                float inv = 1.0f / (sqrtf(var) + 1e-8f);
                smA[w*4 + r] = inv * (LOG2E / 32.0f);
                smC[w*4 + r] = -mu * inv * LOG2E;
            }
        }
    }

    // preload Q B-frags (B[d][q]) while the prologue settles
    bf16x8 bqf0 = ldb(&Qb[(size_t)(q0 + l15) * D_ + 0*32 + g*8]);
    bf16x8 bqf1 = ldb(&Qb[(size_t)(q0 + l15) * D_ + 1*32 + g*8]);
    __syncthreads();
    const float a2v = smA[l15];
    const float c2v = smC[l15];

    floatx4 O[4] = {};
    float sacc = 0.0f;
    short* Pw = &P[w][0][0];

    for (int kc = 0; kc < 256; kc += 64) {
        const int key0 = w * 256 + kc;
        const int kblk16 = (b * S_ + key0) >> 4;
        const int kblk64 = (b * S_ + key0) >> 6;
        // --- S^T tile: D[key][q] ---
        floatx4 Sc[4] = {};
        __builtin_amdgcn_s_setprio(1);
        #pragma unroll
        for (int kt = 0; kt < 4; ++kt) {
            bf16x8 ak0 = ldb(&KF[(size_t)(((kblk16 + kt) * 2 + 0) * 64 + lane) * 8]);
            bf16x8 ak1 = ldb(&KF[(size_t)(((kblk16 + kt) * 2 + 1) * 64 + lane) * 8]);
            Sc[kt] = MFMA(ak0, bqf0, Sc[kt]);
            Sc[kt] = MFMA(ak1, bqf1, Sc[kt]);
        }
        __builtin_amdgcn_s_setprio(0);
        lds_fence();   // WAR: previous chunk's P reads must finish (wave-private P)
        // --- exp2 + pack bf16 + write P[q][key] ---
        #pragma unroll
        for (int kt = 0; kt < 4; ++kt) {
            float w0 = __builtin_amdgcn_exp2f(fmaf(Sc[kt][0], a2v, c2v));
            float w1 = __builtin_amdgcn_exp2f(fmaf(Sc[kt][1], a2v, c2v));
            float w2 = __builtin_amdgcn_exp2f(fmaf(Sc[kt][2], a2v, c2v));
            float w3 = __builtin_amdgcn_exp2f(fmaf(Sc[kt][3], a2v, c2v));
            sacc += (w0 + w1) + (w2 + w3);
            short4 pk;
            pk.x = bfc(w0); pk.y = bfc(w1); pk.z = bfc(w2); pk.w = bfc(w3);
            *(short4*)&Pw[l15 * 72 + kt*16 + 4*g] = pk;
        }
        lds_fence();   // RAW: make P visible to all lanes of this wave
        // --- PV: O[q][d] += P.V ---
        bf16x8 ap0 = ldb(&Pw[l15 * 72 + 0*32 + g*8]);
        bf16x8 ap1 = ldb(&Pw[l15 * 72 + 1*32 + g*8]);
        __builtin_amdgcn_s_setprio(1);
        #pragma unroll
        for (int nt = 0; nt < 4; ++nt) {
            bf16x8 bv0 = ldb(&VF[(size_t)(((kblk64 * 4 + nt) * 2 + 0) * 64 + lane) * 8]);
            bf16x8 bv1 = ldb(&VF[(size_t)(((kblk64 * 4 + nt) * 2 + 1) * 64 + lane) * 8]);
            O[nt] = MFMA(ap0, bv0, O[nt]);
            O[nt] = MFMA(ap1, bv1, O[nt]);
        }
        __builtin_amdgcn_s_setprio(0);
    }

    // --- per-wave epilogue: reduce sumw over g-groups; stash partials in LDS ---
    sacc += __shfl_xor(sacc, 16, 64);
    sacc += __shfl_xor(sacc, 32, 64);
    if (lane < 16) sumwL[w][lane] = sacc;
    #pragma unroll
    for (int nt = 0; nt < 4; ++nt)
        #pragma unroll
        for (int r = 0; r < 4; ++r)
            OL[w][4*g + r][nt*16 + l15] = (short)f2bf(O[nt][r]);
    __syncthreads();

    // --- block reduce: HN = (sum_w OL) / (sum_w sumw) -> A-frags in LDS ---
    {
        const int row = t >> 5;            // 0..15
        const int c = (t & 31) * 2;        // 0..62
        float s0 = 0.f, s1 = 0.f, sw = 0.f;
        #pragma unroll
        for (int p = 0; p < 8; ++p) {
            s0 += bf2f(OL[p][row][c]);
            s1 += bf2f(OL[p][row][c + 1]);
            sw += sumwL[p][row];
        }
        float inv = 1.0f / sw;
        short2 hn;
        hn.x = (short)f2bf(s0 * inv);
        hn.y = (short)f2bf(s1 * inv);
        int kh = c >> 5, g2 = (c >> 3) & 3, j = c & 7;
        *(short2*)&hnF[(kh * 64 + g2 * 16 + row) * 8 + j] = hn;
    }
    __syncthreads();

    // --- out tile [16 x 1024] = HN @ Weff + bout; wave w owns 8 n-tiles ---
    bf16x8 ah0 = ldb(&hnF[(0 * 64 + lane) * 8]);
    bf16x8 ah1 = ldb(&hnF[(1 * 64 + lane) * 8]);
    #pragma unroll
    for (int i = 0; i < 8; ++i) {
        int n16 = w * 8 + i;
        floatx4 acc = {};
        acc = MFMA(ah0, ldb(&WFF[(size_t)(n16 * 2 + 0) * 512 + lane * 8]), acc);
        acc = MFMA(ah1, ldb(&WFF[(size_t)(n16 * 2 + 1) * 512 + lane * 8]), acc);
        int col = n16 * 16 + l15;
        float bb = bout[col];
        #pragma unroll
        for (int r = 0; r < 4; ++r)
            out[(size_t)(q0 + 4*g + r) * H_ + col] = acc[r] + bb;
    }
}

// ---------------------------------------------------------------------------
extern "C" void kernel_launch(void* const* d_in, const int* in_sizes, int n_in,
                              void* d_out, int out_size, void* d_ws, size_t ws_size,
                              hipStream_t stream) {
    const float* query = (const float*)d_in[0];
    const float* key   = (const float*)d_in[1];
    const float* value = (const float*)d_in[2];
    // d_in[3] mask / d_in[12] seq_mask: adding -1e-32 is a no-op in fp32 -> never read.
    const float* Wq   = (const float*)d_in[4];
    const float* bq   = (const float*)d_in[5];
    const float* Wk   = (const float*)d_in[6];
    const float* bk   = (const float*)d_in[7];
    const float* Wv   = (const float*)d_in[8];
    const float* bv   = (const float*)d_in[9];
    const float* Wout = (const float*)d_in[10];
    const float* bout = (const float*)d_in[11];

    float* ws  = (float*)d_ws;
    float* out = (float*)d_out;

    prep<<<177, 256, 0, stream>>>(Wq, Wk, Wv, Wout, ws);
    qkv_mfma<<<dim3(ROWS/32, 3), 256, 0, stream>>>(query, key, value, bq, bk, bv, ws);
    attn_fused<<<ROWS/16, 512, 0, stream>>>(bout, ws, out);
}